// Round 17
// baseline (116.862 us; speedup 1.0000x reference)
//
#include <hip/hip_runtime.h>

#define B_DIM 4096
#define T_DIM 200
#define D_DIM 128
#define H_DIM 16
#define NCH   25    // chunks of 8 rows: 25*8 = 200 exactly

typedef _Float16 h2 __attribute__((ext_vector_type(2)));   // fdot2 operand type
typedef __fp16   g2 __attribute__((ext_vector_type(2)));   // cvt_pkrtz return type
union HU { unsigned int u; h2 h; };

__device__ __forceinline__ h2 pkh(float a, float b) {
    g2 t = __builtin_amdgcn_cvt_pkrtz(a, b);   // v_cvt_pkrtz_f16_f32
    return __builtin_bit_cast(h2, t);
}

// VALU-pipe cross-lane move (v_mov_dpp). 0xB1=quad_perm xor1, 0x4E=quad_perm xor2,
// 0x128=row_ror:8 == xor8 within each 16-lane row.
template<int CTRL>
__device__ __forceinline__ float dppmov(float x) {
    return __builtin_bit_cast(float,
        __builtin_amdgcn_update_dpp(0, __builtin_bit_cast(int, x), CTRL, 0xF, 0xF, true));
}
// DS-pipe lane xor-4: BitMode offset (4<<10)|0x1F
__device__ __forceinline__ float swz4f(float x) {
    return __builtin_bit_cast(float,
        __builtin_amdgcn_ds_swizzle(__builtin_bit_cast(int, x), 0x101F));
}

extern "C" __global__ __launch_bounds__(512)
void din_fused(const float* __restrict__ query,
               const float* __restrict__ facts,
               const int* __restrict__ mask,
               const float* __restrict__ W1,
               const float* __restrict__ b1,
               const float* __restrict__ W2,
               float* __restrict__ out)
{
    const int tid  = threadIdx.x;
    const int wid  = tid >> 6;        // wave = one b
    const int lane = tid & 63;
    const int sub  = lane & 15;       // owns d = sub*8 .. +7
    const int rg   = lane >> 4;       // rows c*8 + 2*rg, +1
    const int b    = blockIdx.x * 8 + wid;

    __shared__ float W1bc[H_DIM * D_DIM];        // (W1b - W1c)[h][d]
    __shared__ float W1dd[H_DIM * D_DIM];        // W1d[h][d]
    __shared__ float W1ac[H_DIM * D_DIM];        // (W1a + W1c)[h][d]
    __shared__ unsigned int wef[8][H_DIM * 64];  // per-wave f16x2 weff, ALL 16 h
    __shared__ float qwl[8][H_DIM];

    const float* fb = facts + (size_t)b * (T_DIM * D_DIM);
    const int*   mb = mask  + (size_t)b * T_DIM;
    const float* qb = query + (size_t)b * D_DIM;

    // ---- mask -> ballot bits (one 800B read per wave; guards become register bits) ----
    unsigned long long bal0, bal1, bal2, bal3;
    {
        int m0 = mb[lane];
        int m1 = mb[64 + lane];
        int m2 = mb[128 + lane];
        int m3 = (lane < 8) ? mb[192 + lane] : 0;
        bal0 = __ballot(m0 != 0);
        bal1 = __ballot(m1 != 0);
        bal2 = __ballot(m2 != 0);
        bal3 = __ballot(m3 != 0);
    }

    // 3-deep rotating prefetch; zero-init so skipped-row garbage is always finite
    float4 FA[2][2] = {}, FB[2][2] = {}, FC[2][2] = {};
    int mvA[2], mvB[2], mvC[2];
    auto loadF = [&](int c, float4 (&F)[2][2], int (&mv)[2]) {
        int r0 = c * 8 + 2 * rg;                 // always < 200; rows r0,r0+1 share a word
        unsigned long long w = r0 < 64 ? bal0 : (r0 < 128 ? bal1 : (r0 < 192 ? bal2 : bal3));
        int sh = r0 & 63;
        mv[0] = (int)((w >> sh) & 1ull);
        mv[1] = (int)((w >> (sh + 1)) & 1ull);
        if (mv[0]) {                              // 16-lane-uniform guard: whole-row elision
            F[0][0] = *(const float4*)(fb + r0 * D_DIM + sub * 8);
            F[0][1] = *(const float4*)(fb + r0 * D_DIM + sub * 8 + 4);
        }
        if (mv[1]) {
            F[1][0] = *(const float4*)(fb + (r0 + 1) * D_DIM + sub * 8);
            F[1][1] = *(const float4*)(fb + (r0 + 1) * D_DIM + sub * 8 + 4);
        }
    };
    loadF(0, FA, mvA);   // chunks 0,1 fly across the whole prologue
    loadF(1, FB, mvB);

    // ---- one-time W1 transpose (only block-wide barrier) ----
    #pragma unroll
    for (int i = 0; i < 4; ++i) {
        int idx = tid * 4 + i;                   // h*128 + d
        int h = idx >> 7, d = idx & 127;
        W1bc[idx] = W1[(128 + d) * H_DIM + h] - W1[(256 + d) * H_DIM + h];
        W1dd[idx] = W1[(384 + d) * H_DIM + h];
        W1ac[idx] = W1[d * H_DIM + h] + W1[(256 + d) * H_DIM + h];
    }
    __syncthreads();

    // ---- per-wave qw ----
    {
        int h = lane & 15, dg = lane >> 4;
        float p = 0.f;
        #pragma unroll
        for (int k = 0; k < 8; ++k) {
            float4 a4 = *(const float4*)&W1ac[h * D_DIM + dg * 32 + 4 * k];
            float4 q4 = *(const float4*)(qb + dg * 32 + 4 * k);
            p += a4.x * q4.x + a4.y * q4.y + a4.z * q4.z + a4.w * q4.w;
        }
        p += __shfl_xor(p, 16);
        p += __shfl_xor(p, 32);
        if (lane < 16) qwl[wid][h] = p + b1[h];
    }
    // ---- weff (ALL 16 h) -> per-wave LDS, f16x2; two 8-h passes ----
    #pragma unroll
    for (int pass = 0; pass < 2; ++pass) {
        int h  = 8 * pass + (lane >> 3);
        int p0 = (lane & 7) * 8;                 // 8 d-pairs per lane
        unsigned int pk[8];
        #pragma unroll
        for (int u = 0; u < 8; ++u) {
            int d0 = 2 * (p0 + u);
            float a0 = W1bc[h * D_DIM + d0]     + qb[d0]     * W1dd[h * D_DIM + d0];
            float a1 = W1bc[h * D_DIM + d0 + 1] + qb[d0 + 1] * W1dd[h * D_DIM + d0 + 1];
            HU t; t.h = pkh(a0, a1); pk[u] = t.u;
        }
        *(uint4*)&wef[wid][h * 64 + p0]     = make_uint4(pk[0], pk[1], pk[2], pk[3]);
        *(uint4*)&wef[wid][h * 64 + p0 + 4] = make_uint4(pk[4], pk[5], pk[6], pk[7]);
    }
    asm volatile("s_waitcnt lgkmcnt(0)" ::: "memory");   // wave-private LDS RAW

    // lane's h after DPP tree over bits {1,2,8}
    const int hg = 4 * (sub & 1) + 2 * ((sub >> 1) & 1) + ((sub >> 3) & 1);
    const float qwA = qwl[wid][hg],     w2A = W2[hg];
    const float qwB = qwl[wid][hg + 8], w2B = W2[hg + 8];
    const unsigned int* wp = &wef[wid][0];

    float a8[8];
    #pragma unroll
    for (int i = 0; i < 8; ++i) a8[i] = 0.f;
    float lloc = 0.f;

    // ---- chunk processor: fdot2 scoring, DPP tree, deferred softmax ----
    // Invalid rows: F holds finite stale/zero data; w -> cndmask 0; 0*finite = 0 exact.
    auto process = [&](float4 (&F)[2][2], int (&mv)[2]) {
        h2 H[2][4];
        #pragma unroll
        for (int r = 0; r < 2; ++r) {
            H[r][0] = pkh(F[r][0].x, F[r][0].y);
            H[r][1] = pkh(F[r][0].z, F[r][0].w);
            H[r][2] = pkh(F[r][1].x, F[r][1].y);
            H[r][3] = pkh(F[r][1].z, F[r][1].w);
        }
        float sc0 = 0.f, sc1 = 0.f;
        #pragma unroll
        for (int g = 0; g < 2; ++g) {
            float hp0[8], hp1[8];
            #pragma unroll
            for (int i = 0; i < 8; ++i) {
                uint4 wl = *(const uint4*)&wp[(g * 8 + i) * 64 + sub * 4];
                HU u0, u1, u2, u3;
                u0.u = wl.x; u1.u = wl.y; u2.u = wl.z; u3.u = wl.w;
                float t0 = 0.f, t1 = 0.f;
                t0 = __builtin_amdgcn_fdot2(u0.h, H[0][0], t0, false);
                t0 = __builtin_amdgcn_fdot2(u1.h, H[0][1], t0, false);
                t0 = __builtin_amdgcn_fdot2(u2.h, H[0][2], t0, false);
                t0 = __builtin_amdgcn_fdot2(u3.h, H[0][3], t0, false);
                t1 = __builtin_amdgcn_fdot2(u0.h, H[1][0], t1, false);
                t1 = __builtin_amdgcn_fdot2(u1.h, H[1][1], t1, false);
                t1 = __builtin_amdgcn_fdot2(u2.h, H[1][2], t1, false);
                t1 = __builtin_amdgcn_fdot2(u3.h, H[1][3], t1, false);
                hp0[i] = t0; hp1[i] = t1;
            }
            // halving tree: bits 1, 2 (quad_perm), 8 (row_ror:8) — all VALU
            #pragma unroll
            for (int i = 0; i < 4; ++i) {
                float k0 = (sub & 1) ? hp0[i + 4] : hp0[i];
                float s0 = (sub & 1) ? hp0[i]     : hp0[i + 4];
                hp0[i] = k0 + dppmov<0xB1>(s0);
                float k1 = (sub & 1) ? hp1[i + 4] : hp1[i];
                float s1 = (sub & 1) ? hp1[i]     : hp1[i + 4];
                hp1[i] = k1 + dppmov<0xB1>(s1);
            }
            #pragma unroll
            for (int i = 0; i < 2; ++i) {
                float k0 = (sub & 2) ? hp0[i + 2] : hp0[i];
                float s0 = (sub & 2) ? hp0[i]     : hp0[i + 2];
                hp0[i] = k0 + dppmov<0x4E>(s0);
                float k1 = (sub & 2) ? hp1[i + 2] : hp1[i];
                float s1 = (sub & 2) ? hp1[i]     : hp1[i + 2];
                hp1[i] = k1 + dppmov<0x4E>(s1);
            }
            {
                float k0 = (sub & 8) ? hp0[1] : hp0[0];
                float s0 = (sub & 8) ? hp0[0] : hp0[1];
                hp0[0] = k0 + dppmov<0x128>(s0);
                float k1 = (sub & 8) ? hp1[1] : hp1[0];
                float s1 = (sub & 8) ? hp1[0] : hp1[1];
                hp1[0] = k1 + dppmov<0x128>(s1);
            }
            hp0[0] += swz4f(hp0[0]);             // d-half join: lane bit 4 (DS)
            hp1[0] += swz4f(hp1[0]);
            float qs = g ? qwB : qwA, ws = g ? w2B : w2A;
            sc0 += ws / (1.f + __expf(-(qs + hp0[0])));
            sc1 += ws / (1.f + __expf(-(qs + hp1[0])));
        }
        // broadcast-sum over bits {1,2,8} (VALU DPP)
        sc0 += dppmov<0xB1>(sc0);
        sc0 += dppmov<0x4E>(sc0);
        sc0 += dppmov<0x128>(sc0);
        sc1 += dppmov<0xB1>(sc1);
        sc1 += dppmov<0x4E>(sc1);
        sc1 += dppmov<0x128>(sc1);
        float w0 = mv[0] ? __expf(sc0) : 0.f;    // deferred softmax: |sc| <= sum|W2|
        float w1 = mv[1] ? __expf(sc1) : 0.f;
        lloc += w0 + w1;
        #pragma unroll
        for (int j = 0; j < 4; ++j) {
            a8[2*j]     += w0 * (float)H[0][j].x + w1 * (float)H[1][j].x;
            a8[2*j + 1] += w0 * (float)H[0][j].y + w1 * (float)H[1][j].y;
        }
    };

    // ---- main loop: 3-deep rotating prefetch (loads 2 process-calls ahead) ----
    #pragma unroll 1
    for (int c = 0; c < 24; c += 3) {
        loadF(c + 2, FC, mvC);
        process(FA, mvA);                        // chunk c
        loadF(c + 3, FA, mvA);
        process(FB, mvB);                        // chunk c+1
        if (c + 4 < NCH) loadF(c + 4, FB, mvB);  // skipped only at c=21
        process(FC, mvC);                        // chunk c+2
    }
    process(FA, mvA);                            // chunk 24

    // ---- epilogue: reduce l over rowgroups; halving-reduce a8; store ----
    float l = lloc;
    l += __shfl_xor(l, 16);
    l += __shfl_xor(l, 32);
    #pragma unroll
    for (int i = 0; i < 4; ++i) {
        float kp = (rg & 1) ? a8[i + 4] : a8[i];
        float sd = (rg & 1) ? a8[i]     : a8[i + 4];
        a8[i] = kp + __shfl_xor(sd, 16);
    }
    #pragma unroll
    for (int i = 0; i < 2; ++i) {
        float kp = (rg & 2) ? a8[i + 2] : a8[i];
        float sd = (rg & 2) ? a8[i]     : a8[i + 2];
        a8[i] = kp + __shfl_xor(sd, 32);
    }
    int dl = sub * 8 + 4 * (rg & 1) + 2 * ((rg >> 1) & 1);
    float inv = 1.f / l;
    *(float2*)(out + (size_t)b * D_DIM + dl) = make_float2(a8[0] * inv, a8[1] * inv);
}

extern "C" void kernel_launch(void* const* d_in, const int* in_sizes, int n_in,
                              void* d_out, int out_size, void* d_ws, size_t ws_size,
                              hipStream_t stream) {
    const float* query = (const float*)d_in[0];
    const float* facts = (const float*)d_in[1];
    const int*   mask  = (const int*)d_in[2];   // harness delivers bool as int32
    const float* W1    = (const float*)d_in[3];
    const float* b1    = (const float*)d_in[4];
    const float* W2    = (const float*)d_in[5];
    // d_in[6] = b2: dropped (cancels in softmax ratio)
    float* out = (float*)d_out;
    (void)in_sizes; (void)n_in; (void)out_size; (void)d_ws; (void)ws_size;

    din_fused<<<dim3(B_DIM / 8), dim3(512), 0, stream>>>(
        query, facts, mask, W1, b1, W2, out);
}

// Round 18
// 93.407 us; speedup vs baseline: 1.2511x; 1.2511x over previous
//
#include <hip/hip_runtime.h>

#define B_DIM 4096
#define T_DIM 200
#define D_DIM 128
#define H_DIM 16
#define NCH   13    // chunks of 16 rows: 13*16 = 208; rows 200-207 masked off

typedef _Float16 h2 __attribute__((ext_vector_type(2)));
typedef _Float16 h8 __attribute__((ext_vector_type(8)));   // MFMA f16 operand
typedef __fp16   g2 __attribute__((ext_vector_type(2)));   // cvt_pkrtz return type
typedef float    f4 __attribute__((ext_vector_type(4)));   // MFMA accumulator
union F8 { h8 v; h2 p[4]; unsigned int u[4]; };
union HU { unsigned int u; h2 h; };

__device__ __forceinline__ h2 pkh(float a, float b) {
    g2 t = __builtin_amdgcn_cvt_pkrtz(a, b);   // v_cvt_pkrtz_f16_f32
    return __builtin_bit_cast(h2, t);
}
// VALU-pipe cross-lane move (v_mov_dpp). 0x12N = row_ror:N within each 16-lane row.
template<int CTRL>
__device__ __forceinline__ float dppmov(float x) {
    return __builtin_bit_cast(float,
        __builtin_amdgcn_update_dpp(0, __builtin_bit_cast(int, x), CTRL, 0xF, 0xF, true));
}
// full sum over the 16 lanes of a row via rotations (all VALU, no DS)
__device__ __forceinline__ float rorsum16(float x) {
    x += dppmov<0x121>(x);
    x += dppmov<0x122>(x);
    x += dppmov<0x124>(x);
    x += dppmov<0x128>(x);
    return x;
}

extern "C" __global__ __launch_bounds__(512)
void din_fused(const float* __restrict__ query,
               const float* __restrict__ facts,
               const int* __restrict__ mask,
               const float* __restrict__ W1,
               const float* __restrict__ b1,
               const float* __restrict__ W2,
               float* __restrict__ out)
{
    const int tid  = threadIdx.x;
    const int wid  = tid >> 6;        // wave = one b
    const int lane = tid & 63;
    const int rl   = lane & 15;       // A-row slot / B-col (=h) / D-col
    const int g    = lane >> 4;       // k-group; D rows 4g..4g+3
    const int b    = blockIdx.x * 8 + wid;

    __shared__ float W1bc[H_DIM * D_DIM];        // (W1b - W1c)[h][d]
    __shared__ float W1dd[H_DIM * D_DIM];        // W1d[h][d]
    __shared__ float W1ac[H_DIM * D_DIM];        // (W1a + W1c)[h][d]
    __shared__ unsigned int wef[8][H_DIM * 64];  // per-wave f16x2 weff staging
    __shared__ float qwl[8][H_DIM];
    __shared__ float wxch[8][16];                // per-wave softmax-weight exchange

    const float* fb = facts + (size_t)b * (T_DIM * D_DIM);
    const int*   mb = mask  + (size_t)b * T_DIM;
    const float* qb = query + (size_t)b * D_DIM;

    // ---- facts chunk-0 loads FIRST (fly across whole prologue) ----
    // Lane holds A-fragment data: row rl, d = 32s + 8g + e (e=0..7)
    float4 F[8];
    auto loadF = [&](int c) {
        int r = 16 * c + rl; if (r > T_DIM - 1) r = T_DIM - 1;   // tail clamp
        const float* p = fb + r * D_DIM + 8 * g;
        #pragma unroll
        for (int s = 0; s < 4; ++s) {
            F[2*s]     = *(const float4*)(p + 32 * s);
            F[2*s + 1] = *(const float4*)(p + 32 * s + 4);
        }
    };
    loadF(0);

    // ---- mask -> ballot bits (one read per wave; guards = register bits) ----
    unsigned long long bal0, bal1, bal2, bal3;
    {
        int m0 = mb[lane];
        int m1 = mb[64 + lane];
        int m2 = mb[128 + lane];
        int m3 = (lane < 8) ? mb[192 + lane] : 0;   // rows >=200 masked off
        bal0 = __ballot(m0 != 0);
        bal1 = __ballot(m1 != 0);
        bal2 = __ballot(m2 != 0);
        bal3 = __ballot(m3 != 0);
    }

    // ---- one-time W1 transpose (only block-wide barrier) ----
    #pragma unroll
    for (int i = 0; i < 4; ++i) {
        int idx = tid * 4 + i;                   // h*128 + d
        int h = idx >> 7, d = idx & 127;
        W1bc[idx] = W1[(128 + d) * H_DIM + h] - W1[(256 + d) * H_DIM + h];
        W1dd[idx] = W1[(384 + d) * H_DIM + h];
        W1ac[idx] = W1[d * H_DIM + h] + W1[(256 + d) * H_DIM + h];
    }
    __syncthreads();

    // ---- per-wave qw ----
    {
        int h = lane & 15, dg = lane >> 4;
        float p = 0.f;
        #pragma unroll
        for (int k = 0; k < 8; ++k) {
            float4 a4 = *(const float4*)&W1ac[h * D_DIM + dg * 32 + 4 * k];
            float4 q4 = *(const float4*)(qb + dg * 32 + 4 * k);
            p += a4.x * q4.x + a4.y * q4.y + a4.z * q4.z + a4.w * q4.w;
        }
        p += __shfl_xor(p, 16);
        p += __shfl_xor(p, 32);
        if (lane < 16) qwl[wid][h] = p + b1[h];
    }
    // ---- weff -> per-wave LDS staging (conflict-free build), f16x2 ----
    #pragma unroll
    for (int pass = 0; pass < 2; ++pass) {
        int h  = 8 * pass + (lane >> 3);
        int p0 = (lane & 7) * 8;                 // 8 d-pairs per lane
        unsigned int pk[8];
        #pragma unroll
        for (int u = 0; u < 8; ++u) {
            int d0 = 2 * (p0 + u);
            float a0 = W1bc[h * D_DIM + d0]     + qb[d0]     * W1dd[h * D_DIM + d0];
            float a1 = W1bc[h * D_DIM + d0 + 1] + qb[d0 + 1] * W1dd[h * D_DIM + d0 + 1];
            HU t; t.h = pkh(a0, a1); pk[u] = t.u;
        }
        *(uint4*)&wef[wid][h * 64 + p0]     = make_uint4(pk[0], pk[1], pk[2], pk[3]);
        *(uint4*)&wef[wid][h * 64 + p0 + 4] = make_uint4(pk[4], pk[5], pk[6], pk[7]);
    }
    asm volatile("s_waitcnt lgkmcnt(0)" ::: "memory");   // wave-private LDS RAW

    // ---- gather B-fragments: lane = col h=rl, k = 32s + 8g + e (one-time) ----
    F8 fB[4];
    #pragma unroll
    for (int s = 0; s < 4; ++s) {
        uint4 t = *(const uint4*)&wef[wid][rl * 64 + 16 * s + 4 * g];
        fB[s].u[0] = t.x; fB[s].u[1] = t.y; fB[s].u[2] = t.z; fB[s].u[3] = t.w;
    }
    const float qv  = qwl[wid][rl];
    const float w2v = W2[rl];

    float a32[32];
    #pragma unroll
    for (int i = 0; i < 32; ++i) a32[i] = 0.f;
    float lw = 0.f;

    // ---- main loop: convert-then-reload pipelining, MFMA scoring ----
    #pragma unroll 1
    for (int c = 0; c < NCH; ++c) {
        F8 fa[4];                                // A-fragments (F dies here)
        #pragma unroll
        for (int s = 0; s < 4; ++s) {
            fa[s].p[0] = pkh(F[2*s].x,     F[2*s].y);
            fa[s].p[1] = pkh(F[2*s].z,     F[2*s].w);
            fa[s].p[2] = pkh(F[2*s + 1].x, F[2*s + 1].y);
            fa[s].p[3] = pkh(F[2*s + 1].z, F[2*s + 1].w);
        }
        if (c + 1 < NCH) loadF(c + 1);           // next chunk lands under compute

        f4 D = {0.f, 0.f, 0.f, 0.f};             // D[j] = pre[16c + 4g + j][h=rl]
        D = __builtin_amdgcn_mfma_f32_16x16x32_f16(fa[0].v, fB[0].v, D, 0, 0, 0);
        D = __builtin_amdgcn_mfma_f32_16x16x32_f16(fa[1].v, fB[1].v, D, 0, 0, 0);
        D = __builtin_amdgcn_mfma_f32_16x16x32_f16(fa[2].v, fB[2].v, D, 0, 0, 0);
        D = __builtin_amdgcn_mfma_f32_16x16x32_f16(fa[3].v, fB[3].v, D, 0, 0, 0);

        int r0 = 16 * c;
        unsigned long long wrd = r0 < 64 ? bal0 : r0 < 128 ? bal1 : r0 < 192 ? bal2 : bal3;
        unsigned long long sw  = wrd >> ((r0 & 63) + 4 * g);

        float wj[4];
        #pragma unroll
        for (int j = 0; j < 4; ++j) {
            float sc = w2v / (1.f + __expf(-(qv + D[j])));   // h-contribution
            sc = rorsum16(sc);                                // sum 16 h (VALU only)
            wj[j] = ((sw >> j) & 1) ? __expf(sc) : 0.f;       // deferred softmax
        }
        lw += wj[0] + wj[1] + wj[2] + wj[3];      // identical across group g

        if (rl == 0)                              // w-exchange: rows -> row-slot lanes
            *(float4*)&wxch[wid][4 * g] = make_float4(wj[0], wj[1], wj[2], wj[3]);
        asm volatile("s_waitcnt lgkmcnt(0)" ::: "memory");
        float wv = wxch[wid][rl];                 // weight of this lane's A-row

        #pragma unroll
        for (int s = 0; s < 4; ++s)
            #pragma unroll
            for (int e = 0; e < 4; ++e) {
                a32[8*s + 2*e]     += wv * (float)fa[s].p[e].x;
                a32[8*s + 2*e + 1] += wv * (float)fa[s].p[e].y;
            }
    }

    // ---- epilogue: l over 4 groups; acc over 16 row-slots (rotation-sum); store ----
    float l = lw;
    l += __shfl_xor(l, 16);
    l += __shfl_xor(l, 32);
    float inv = 1.f / l;
    #pragma unroll
    for (int i = 0; i < 32; ++i) a32[i] = rorsum16(a32[i]);
    if (rl == 0) {                                // group g writes d = 32s + 8g + 0..7
        float* ob = out + (size_t)b * D_DIM + 8 * g;
        #pragma unroll
        for (int s = 0; s < 4; ++s) {
            *(float4*)(ob + 32 * s) =
                make_float4(a32[8*s]*inv, a32[8*s+1]*inv, a32[8*s+2]*inv, a32[8*s+3]*inv);
            *(float4*)(ob + 32 * s + 4) =
                make_float4(a32[8*s+4]*inv, a32[8*s+5]*inv, a32[8*s+6]*inv, a32[8*s+7]*inv);
        }
    }
}

extern "C" void kernel_launch(void* const* d_in, const int* in_sizes, int n_in,
                              void* d_out, int out_size, void* d_ws, size_t ws_size,
                              hipStream_t stream) {
    const float* query = (const float*)d_in[0];
    const float* facts = (const float*)d_in[1];
    const int*   mask  = (const int*)d_in[2];   // harness delivers bool as int32
    const float* W1    = (const float*)d_in[3];
    const float* b1    = (const float*)d_in[4];
    const float* W2    = (const float*)d_in[5];
    // d_in[6] = b2: dropped (cancels in softmax ratio)
    float* out = (float*)d_out;
    (void)in_sizes; (void)n_in; (void)out_size; (void)d_ws; (void)ws_size;

    din_fused<<<dim3(B_DIM / 8), dim3(512), 0, stream>>>(
        query, facts, mask, W1, b1, W2, out);
}